// Round 5
// baseline (398.013 us; speedup 1.0000x reference)
//
#include <hip/hip_runtime.h>

// LSTM B=4096, T=512, I=1, H=64, O=1 (fp32 in/out).
// Round 5: MB=4, grid=1024 (4 blocks/CU -> 4 independent chains per SIMD for
// barrier-stall hiding). hi/lo packed in M + DUPLICATED into rows 8..15:
//   A rows: m=2q+p and m=8+2q+p both hold plane p of batch q (p=0 hi,1 lo).
// => every lane's acc regs hold a valid cell's gates:
//   h0=0: batch0 via acc[0]+acc[1]; h0=1: batch2 via acc[0]+acc[1];
//   h0=2: batch1 via acc[2]+acc[3]; h0=3: batch3 via acc[2]+acc[3].
// 1 cell/lane, zero shuffles, trans issue at device floor. MFMA 2x redundant
// (pipe has headroom). One barrier/step, ping-pong h buffers.
// MFMA layouts (m89-verified): A[m=lane&15][k=(lane>>4)*8+i],
// B[k=(lane>>4)*8+i][n=lane&15], D[m=(lane>>4)*4+r][n=lane&15].

#define TT   512
#define MB   4
#define HP   72            // f16 row stride (144 B): 16B-aligned, 2-way max
#define BUFE (16 * HP)     // one ping-pong buffer: 16 rows
#define SXP  5             // sh_x row stride (floats): odd -> 2-way max

typedef _Float16 f16x8 __attribute__((ext_vector_type(8)));
typedef float    f32x4 __attribute__((ext_vector_type(4)));

#define MFMA16(a, b, c) __builtin_amdgcn_mfma_f32_16x16x32_f16((a), (b), (c), 0, 0, 0)

__device__ __forceinline__ float rcp_(float x) { return __builtin_amdgcn_rcpf(x); }
__device__ __forceinline__ float sigmoid_(float x) { return rcp_(1.0f + __expf(-x)); }
__device__ __forceinline__ float tanh_(float x) { return 1.0f - 2.0f * rcp_(1.0f + __expf(2.0f * x)); }

__device__ __forceinline__ f16x8 cvt8(const float4& u0, const float4& u1) {
    f16x8 r;
    r[0] = (_Float16)u0.x; r[1] = (_Float16)u0.y; r[2] = (_Float16)u0.z; r[3] = (_Float16)u0.w;
    r[4] = (_Float16)u1.x; r[5] = (_Float16)u1.y; r[6] = (_Float16)u1.z; r[7] = (_Float16)u1.w;
    return r;
}

__global__ __launch_bounds__(256, 4) void lstm_mfma(
    const float* __restrict__ x,      // [4096, 512]
    const float* __restrict__ w_ih,   // [256]
    const float* __restrict__ w_hh,   // [256, 64]
    const float* __restrict__ b_ih,   // [256]
    const float* __restrict__ b_hh,   // [256]
    const float* __restrict__ w_out,  // [64]
    const float* __restrict__ b_out,  // [1]
    float* __restrict__ out)          // [4096]
{
    __shared__ __align__(16) float    sh_x[TT * SXP];   // [t][q], 10 KB
    __shared__ __align__(16) _Float16 hbuf[2 * BUFE];   // 4.6 KB

    const int tid = threadIdx.x;
    const int w   = tid >> 6;    // wave 0..3 (owns N-tiles {w, w+4, w+8, w+12})
    const int L   = tid & 63;
    const int l16 = L & 15;
    const int h0  = L >> 4;      // 0..3
    const int b0  = blockIdx.x * MB;
    const int j   = 16 * w + l16;  // hidden unit col owned by this lane

    // ---- stage x: wave w loads batch w (coalesced; 2-way LDS alias) ----
    {
        const float* xr = x + (size_t)(b0 + w) * TT;
        #pragma unroll
        for (int i = 0; i < TT / 64; ++i)
            sh_x[(L + 64 * i) * SXP + w] = xr[L + 64 * i];
    }
    // ---- zero both h buffers ----
    for (int i = tid; i < 2 * BUFE; i += 256) hbuf[i] = (_Float16)0.0f;

    // ---- preload W_hh fragments (fp16-rounded once) ----
    f16x8 Bf[4][2];
    float wihv[4], biasv[4];
    #pragma unroll
    for (int s = 0; s < 4; ++s) {
        const int n = 64 * s + j;
        #pragma unroll
        for (int kt = 0; kt < 2; ++kt) {
            const float* p = w_hh + n * 64 + kt * 32 + h0 * 8;
            float4 u0 = *(const float4*)p;
            float4 u1 = *(const float4*)(p + 4);
            Bf[s][kt] = cvt8(u0, u1);
        }
        wihv[s]  = w_ih[n];
        biasv[s] = b_ih[n] + b_hh[n];
    }

    // lane's cell: q = {0,2,1,3}[h0]; gates from acc[0]+acc[1] (h0<2) or
    // acc[2]+acc[3] (h0>=2). Writes hi/lo to rows 2q,2q+1 and dups 8+2q,9+2q.
    const int  q      = (h0 & 1) * 2 + (h0 >> 1);
    const bool lopair = (h0 < 2);
    const int  wr0    = (2 * q) * HP + j;
    const int  aoff   = l16 * HP + h0 * 8;   // f16 units; +32 for K-chunk 1

    float cc = 0.0f;
    __syncthreads();

    auto step = [&](const _Float16* rb, _Float16* wb, int t) {
        f16x8 a0 = *(const f16x8*)(rb + aoff);
        f16x8 a1 = *(const f16x8*)(rb + aoff + 32);

        const f32x4 z = {0.f, 0.f, 0.f, 0.f};
        f32x4 acc0 = MFMA16(a1, Bf[0][1], MFMA16(a0, Bf[0][0], z));
        f32x4 acc1 = MFMA16(a1, Bf[1][1], MFMA16(a0, Bf[1][0], z));
        f32x4 acc2 = MFMA16(a1, Bf[2][1], MFMA16(a0, Bf[2][0], z));
        f32x4 acc3 = MFMA16(a1, Bf[3][1], MFMA16(a0, Bf[3][0], z));

        float g0 = lopair ? (acc0[0] + acc0[1]) : (acc0[2] + acc0[3]);
        float g1 = lopair ? (acc1[0] + acc1[1]) : (acc1[2] + acc1[3]);
        float g2 = lopair ? (acc2[0] + acc2[1]) : (acc2[2] + acc2[3]);
        float g3 = lopair ? (acc3[0] + acc3[1]) : (acc3[2] + acc3[3]);

        const float xv = sh_x[t * SXP + q];
        float gi = g0 + fmaf(xv, wihv[0], biasv[0]);
        float gf = g1 + fmaf(xv, wihv[1], biasv[1]);
        float gg = g2 + fmaf(xv, wihv[2], biasv[2]);
        float go = g3 + fmaf(xv, wihv[3], biasv[3]);
        float i_ = sigmoid_(gi), f_ = sigmoid_(gf);
        float g_ = tanh_(gg),   o_ = sigmoid_(go);
        cc = fmaf(f_, cc, i_ * g_);
        float hv = o_ * tanh_(cc);
        _Float16 hh = (_Float16)hv;
        _Float16 hl = (_Float16)(hv - (float)hh);
        wb[wr0]          = hh;   // row 2q   (hi)
        wb[wr0 + HP]     = hl;   // row 2q+1 (lo)
        wb[wr0 + 8 * HP] = hh;   // row 8+2q (dup hi)
        wb[wr0 + 9 * HP] = hl;   // row 9+2q (dup lo)
        __syncthreads();
    };

    for (int t = 0; t < TT; t += 2) {
        step(hbuf,        hbuf + BUFE, t);      // read buf0, write buf1
        step(hbuf + BUFE, hbuf,        t + 1);  // read buf1, write buf0
    }

    // ---- epilogue: final h in buf0; wave w reduces batch w ----
    const float wo = w_out[L];
    float hvf = (float)hbuf[(2 * w) * HP + L] + (float)hbuf[(2 * w + 1) * HP + L];
    float v = hvf * wo;
    #pragma unroll
    for (int off = 32; off; off >>= 1) v += __shfl_down(v, off);
    if (L == 0) out[b0 + w] = v + b_out[0];
}

extern "C" void kernel_launch(void* const* d_in, const int* in_sizes, int n_in,
                              void* d_out, int out_size, void* d_ws, size_t ws_size,
                              hipStream_t stream) {
    const float* x     = (const float*)d_in[0];
    const float* w_ih  = (const float*)d_in[1];
    const float* w_hh  = (const float*)d_in[2];
    const float* b_ih  = (const float*)d_in[3];
    const float* b_hh  = (const float*)d_in[4];
    const float* w_out = (const float*)d_in[5];
    const float* b_out = (const float*)d_in[6];
    float* out = (float*)d_out;

    lstm_mfma<<<4096 / MB, 256, 0, stream>>>(x, w_ih, w_hh, b_ih, b_hh,
                                             w_out, b_out, out);
}